// Round 5
// baseline (192.493 us; speedup 1.0000x reference)
//
#include <hip/hip_runtime.h>
#include <stdint.h>

#define BSZ   16
#define LSEQ  4096
#define HDIM  128
#define PDIM  256
#define TCHB  128                 // rows per block
#define NSUB  4                   // sub-chunks of 32 rows
#define CHUNKS (LSEQ/TCHB)        // 32

typedef __attribute__((ext_vector_type(4)))  float  f32x4;
typedef __attribute__((ext_vector_type(16))) float  f32x16;
typedef __attribute__((ext_vector_type(8)))  __bf16 bf16x8;

// ---------------- workspace layout (bytes) ----------------
constexpr size_t WS_COEF  = 0;                                   // 6*256 floats
constexpr size_t WS_MPOW2 = 8192;                                // 7*4*256 floats
constexpr size_t WS_WB    = 40960;                               // 128 KB frag-packed Wb (32x32x16 tiles)
constexpr size_t WS_WC    = WS_WB + 131072;                      // 128 KB frag-packed Wc (16x16x32 tiles)
constexpr size_t PLANE    = (size_t)BSZ * CHUNKS * PDIM;         // 131072 float2 per plane
constexpr size_t WS_ENDS  = WS_WC + 131072;                      // 2 planes * 1 MB = 2 MB
constexpr size_t WS_CARR  = WS_ENDS + 2 * PLANE * 8;             // 2 MB

__device__ __forceinline__ unsigned short f2bf(float f) {
  unsigned u = __float_as_uint(f);
  u = (u + 0x7fffu + ((u >> 16) & 1u)) >> 16;   // RNE
  return (unsigned short)u;
}

__device__ __forceinline__ bf16x8 cvt8(float4 f0, float4 f1v) {
  bf16x8 a;
  a[0]=(__bf16)f0.x;  a[1]=(__bf16)f0.y;  a[2]=(__bf16)f0.z;  a[3]=(__bf16)f0.w;
  a[4]=(__bf16)f1v.x; a[5]=(__bf16)f1v.y; a[6]=(__bf16)f1v.z; a[7]=(__bf16)f1v.w;
  return a;
}

// ---------------- K1: weight packing + (block 0) coefficients & powers ----------------
// Wb (32x32x16 B-frag): tiles ct(16) x kt(8); lane l: col=ct*32+(l&31), k=kt*16+(l>>5)*8+e (k=h)
// Wc (16x16x32 B-frag): tiles ct(8) x kt(16); lane l: col=ct*16+(l&15), k=kt*32+(l>>4)*8+e,
//     with k -> (p = k>>1, c = k&1)  [re/im interleaved to match xst layout]
__global__ __launch_bounds__(256) void prep_kernel(const float* __restrict__ A_diag,
                                                   const float* __restrict__ G_diag,
                                                   const float* __restrict__ dtp,
                                                   const float* __restrict__ B,
                                                   const float* __restrict__ C,
                                                   float* __restrict__ coef,
                                                   float* __restrict__ mpow2,
                                                   ushort* __restrict__ Wb,
                                                   ushort* __restrict__ Wc) {
  if (blockIdx.x == 0) {
    int p = threadIdx.x;
    float dt_s = 1.0f / (1.0f + expf(-dtp[p]));
    float A = fmaxf(A_diag[p], 0.0f);
    float G = fmaxf(G_diag[p], 0.0f);
    float root  = sqrtf(1.0f + dt_s * G);
    float denom = fmaxf(dt_s * dt_s, 1e-6f);
    float A_low  = (2.0f + dt_s * G - 2.0f * root) / denom;
    float A_high = (2.0f + dt_s * G + 2.0f * root) / denom;
    A = A_low + fmaxf(A - A_low, 0.0f) - fmaxf(A - A_high, 0.0f);
    float S  = 1.0f / (1.0f + dt_s * G);
    float mA = S;
    float mB = -A * dt_s * S;
    float mC = dt_s * S;
    float mD = 1.0f - A * dt_s * dt_s * S;
    coef[0*PDIM + p] = mA;
    coef[1*PDIM + p] = mB;
    coef[2*PDIM + p] = mC;
    coef[3*PDIM + p] = mD;
    coef[4*PDIM + p] = dt_s;
    float a = mA, b = mB, c = mC, d = mD;
    #pragma unroll
    for (int i = 0; i < 5; i++) {   // -> M^32
      float na = a*a + b*c, nb = a*b + b*d, nc = c*a + d*c, nd = c*b + d*d;
      a = na; b = nb; c = nc; d = nd;
    }
    mpow2[(0*4+0)*PDIM + p] = a; mpow2[(0*4+1)*PDIM + p] = b;
    mpow2[(0*4+2)*PDIM + p] = c; mpow2[(0*4+3)*PDIM + p] = d;
    #pragma unroll
    for (int j = 1; j < 7; j++) {
      float na = a*a + b*c, nb = a*b + b*d, nc = c*a + d*c, nd = c*b + d*d;
      a = na; b = nb; c = nc; d = nd;
      mpow2[(j*4+0)*PDIM + p] = a; mpow2[(j*4+1)*PDIM + p] = b;
      mpow2[(j*4+2)*PDIM + p] = c; mpow2[(j*4+3)*PDIM + p] = d;
    }
  }

  int idx = blockIdx.x * 256 + threadIdx.x;   // 0..131071
  if (idx < 65536) {
    int e  = idx & 7;
    int l  = (idx >> 3) & 63;
    int kt = (idx >> 9) & 7;
    int ct = idx >> 12;                 // 0..15
    int k   = kt*16 + (l >> 5)*8 + e;   // h, 0..127
    int col = ct*32 + (l & 31);         // 0..511
    int c = col >> 8, p = col & 255;
    float dts = 1.0f / (1.0f + expf(-dtp[p]));
    float G = fmaxf(G_diag[p], 0.0f);
    float f1 = dts / (1.0f + dts * G);  // dt_s * S
    Wb[idx] = f2bf(B[(size_t)p*2*HDIM + k*2 + c] * f1);
  } else {
    int j  = idx - 65536;
    int e  = j & 7;
    int l  = (j >> 3) & 63;
    int kt = (j >> 9) & 15;
    int ct = j >> 13;                   // 0..7
    int k = kt*32 + (l >> 4)*8 + e;     // 0..511
    int h = ct*16 + (l & 15);
    int c = k & 1, p = k >> 1;          // interleaved
    float v = C[(size_t)h*2*PDIM + p*2 + c];
    Wc[j] = f2bf(c ? -v : v);
  }
}

// ---------------- K_A: 128-row block: bu-GEMM + continuous register scan -> ends ----------------
__global__ __launch_bounds__(256) void ka_kernel(const float* __restrict__ u,
                                                 const ushort* __restrict__ Wb,
                                                 const float* __restrict__ coef,
                                                 float2* __restrict__ ends2) {
  int tid = threadIdx.x;
  int l = tid & 63, w = tid >> 6;
  int l31 = l & 31, hi = l >> 5;
  int cb = blockIdx.x, b = blockIdx.y;
  size_t row0 = (size_t)b * LSEQ + (size_t)cb * TCHB;

  int pa = w*64 + l31, pb = pa + 32;
  float mAa = coef[pa], mBa = coef[256+pa], mCa = coef[512+pa], mDa = coef[768+pa], dsa = coef[1024+pa];
  float mAb = coef[pb], mBb = coef[256+pb], mCb = coef[512+pb], mDb = coef[768+pb], dsb = coef[1024+pb];

  const ushort* wbb = Wb + (size_t)l * 8;
  float v1a = 0.f, v2a = 0.f, v1b = 0.f, v2b = 0.f;

  for (int s = 0; s < NSUB; s++) {
    f32x16 accRa = {}, accRb = {}, accIa = {}, accIb = {};
    const float* abase = u + (row0 + s*32 + l31) * HDIM + hi * 8;
    #pragma unroll
    for (int kt = 0; kt < 8; kt++) {
      float4 f0  = *(const float4*)(abase + kt*16);
      float4 f1v = *(const float4*)(abase + kt*16 + 4);
      bf16x8 a = cvt8(f0, f1v);
      bf16x8 bRa = *(const bf16x8*)(wbb + ((2*w    )*8 + kt)*512);
      bf16x8 bRb = *(const bf16x8*)(wbb + ((2*w + 1)*8 + kt)*512);
      bf16x8 bIa = *(const bf16x8*)(wbb + ((2*w + 8)*8 + kt)*512);
      bf16x8 bIb = *(const bf16x8*)(wbb + ((2*w + 9)*8 + kt)*512);
      accRa = __builtin_amdgcn_mfma_f32_32x32x16_bf16(a, bRa, accRa, 0, 0, 0);
      accRb = __builtin_amdgcn_mfma_f32_32x32x16_bf16(a, bRb, accRb, 0, 0, 0);
      accIa = __builtin_amdgcn_mfma_f32_32x32x16_bf16(a, bIa, accIa, 0, 0, 0);
      accIb = __builtin_amdgcn_mfma_f32_32x32x16_bf16(a, bIb, accIb, 0, 0, 0);
    }

    float s0a[16], s1a[16], s0b[16], s1b[16];
    #pragma unroll
    for (int r = 0; r < 16; r++) {
      float ya = hi ? accRa[r] : accIa[r];
      float Oa = __shfl_xor(ya, 32);
      float Ma = hi ? accIa[r] : accRa[r];
      s0a[r] = hi ? Oa : Ma;
      s1a[r] = hi ? Ma : Oa;
      float yb = hi ? accRb[r] : accIb[r];
      float Ob = __shfl_xor(yb, 32);
      float Mb = hi ? accIb[r] : accRb[r];
      s0b[r] = hi ? Ob : Mb;
      s1b[r] = hi ? Mb : Ob;
    }

    #pragma unroll
    for (int t = 0; t < 32; t++) {
      const int r = (t & 3) | ((t >> 3) << 2);
      float fa = ((t >> 2) & 1) ? s1a[r] : s0a[r];
      float fb = ((t >> 2) & 1) ? s1b[r] : s0b[r];
      float n1a = fmaf(mAa, v1a, fmaf(mBa, v2a, fa));
      float n2a = fmaf(mCa, v1a, fmaf(mDa, v2a, dsa * fa));
      float n1b = fmaf(mAb, v1b, fmaf(mBb, v2b, fb));
      float n2b = fmaf(mCb, v1b, fmaf(mDb, v2b, dsb * fb));
      v1a = n1a; v2a = n2a; v1b = n1b; v2b = n2b;
    }
  }

  size_t ebase = (size_t)hi * PLANE + ((size_t)b * CHUNKS + cb) * PDIM;
  ends2[ebase + pa] = make_float2(v1a, v2a);
  ends2[ebase + pb] = make_float2(v1b, v2b);
}

// ---------------- K_carry: serial per-p combine over 32 chunks (fully coalesced) ----------------
__global__ __launch_bounds__(256) void carry_kernel(const float2* __restrict__ ends2,
                                                    const float* __restrict__ mpow2,
                                                    float2* __restrict__ carr2) {
  int p = threadIdx.x;
  int b = blockIdx.x, plane = blockIdx.y;
  // Q = M^TCHB = M^128 = mpow2[j=2]
  float qA = mpow2[(2*4+0)*PDIM + p], qB = mpow2[(2*4+1)*PDIM + p];
  float qC = mpow2[(2*4+2)*PDIM + p], qD = mpow2[(2*4+3)*PDIM + p];
  size_t base = (size_t)plane * PLANE + (size_t)b * CHUNKS * PDIM + p;
  float2 e[CHUNKS];
  #pragma unroll
  for (int c = 0; c < CHUNKS; c++) e[c] = ends2[base + (size_t)c * PDIM];
  float cx = 0.f, cy = 0.f;
  #pragma unroll
  for (int c = 0; c < CHUNKS; c++) {
    carr2[base + (size_t)c * PDIM] = make_float2(cx, cy);
    float nx = fmaf(qA, cx, fmaf(qB, cy, e[c].x));
    float ny = fmaf(qC, cx, fmaf(qD, cy, e[c].y));
    cx = nx; cy = ny;
  }
}

// ---------------- K_B: 128-row block: bu-GEMM + scan (carry-in) -> xst -> out-GEMM ----------------
__global__ __launch_bounds__(256) void kb_kernel(const float* __restrict__ u,
                                                 const ushort* __restrict__ Wb,
                                                 const ushort* __restrict__ Wc,
                                                 const float* __restrict__ coef,
                                                 const float2* __restrict__ carr2,
                                                 const float* __restrict__ Dv,
                                                 float* __restrict__ out) {
  __shared__ ushort xst[2][32][520];   // 66.6 KB, double-buffered; col = 2*p + c (re/im interleaved)
  int tid = threadIdx.x;
  int l = tid & 63, w = tid >> 6;
  int l31 = l & 31, hi = l >> 5;
  int lr = l & 15, lk = (l >> 4) & 3;
  int cb = blockIdx.x, b = blockIdx.y;
  size_t row0 = (size_t)b * LSEQ + (size_t)cb * TCHB;

  int pa = w*64 + l31, pb = pa + 32;
  float mAa = coef[pa], mBa = coef[256+pa], mCa = coef[512+pa], mDa = coef[768+pa], dsa = coef[1024+pa];
  float mAb = coef[pb], mBb = coef[256+pb], mCb = coef[512+pb], mDb = coef[768+pb], dsb = coef[1024+pb];

  size_t cbase = (size_t)hi * PLANE + ((size_t)b * CHUNKS + cb) * PDIM;
  float2 cva = carr2[cbase + pa];
  float2 cvb = carr2[cbase + pb];
  float v1a = cva.x, v2a = cva.y, v1b = cvb.x, v2b = cvb.y;

  int cola = 2*pa + hi;   // hi=0 -> re slot, hi=1 -> im slot
  int colb = 2*pb + hi;
  const ushort* wbb = Wb + (size_t)l * 8;
  float Dh0 = Dv[2*w*16 + lr];
  float Dh1 = Dv[(2*w+1)*16 + lr];

  for (int s = 0; s < NSUB; s++) {
    // ---- bu GEMM for rows [row0+s*32, +32) ----
    f32x16 accRa = {}, accRb = {}, accIa = {}, accIb = {};
    const float* abase = u + (row0 + s*32 + l31) * HDIM + hi * 8;
    #pragma unroll
    for (int kt = 0; kt < 8; kt++) {
      float4 f0  = *(const float4*)(abase + kt*16);
      float4 f1v = *(const float4*)(abase + kt*16 + 4);
      bf16x8 a = cvt8(f0, f1v);
      bf16x8 bRa = *(const bf16x8*)(wbb + ((2*w    )*8 + kt)*512);
      bf16x8 bRb = *(const bf16x8*)(wbb + ((2*w + 1)*8 + kt)*512);
      bf16x8 bIa = *(const bf16x8*)(wbb + ((2*w + 8)*8 + kt)*512);
      bf16x8 bIb = *(const bf16x8*)(wbb + ((2*w + 9)*8 + kt)*512);
      accRa = __builtin_amdgcn_mfma_f32_32x32x16_bf16(a, bRa, accRa, 0, 0, 0);
      accRb = __builtin_amdgcn_mfma_f32_32x32x16_bf16(a, bRb, accRb, 0, 0, 0);
      accIa = __builtin_amdgcn_mfma_f32_32x32x16_bf16(a, bIa, accIa, 0, 0, 0);
      accIb = __builtin_amdgcn_mfma_f32_32x32x16_bf16(a, bIb, accIb, 0, 0, 0);
    }

    // ---- exchange ----
    float s0a[16], s1a[16], s0b[16], s1b[16];
    #pragma unroll
    for (int r = 0; r < 16; r++) {
      float ya = hi ? accRa[r] : accIa[r];
      float Oa = __shfl_xor(ya, 32);
      float Ma = hi ? accIa[r] : accRa[r];
      s0a[r] = hi ? Oa : Ma;
      s1a[r] = hi ? Ma : Oa;
      float yb = hi ? accRb[r] : accIb[r];
      float Ob = __shfl_xor(yb, 32);
      float Mb = hi ? accIb[r] : accRb[r];
      s0b[r] = hi ? Ob : Mb;
      s1b[r] = hi ? Mb : Ob;
    }

    // ---- scan 32 steps, emit xs rows into xst[s&1] ----
    ushort (*xb)[520] = xst[s & 1];
    #pragma unroll
    for (int t = 0; t < 32; t++) {
      const int r = (t & 3) | ((t >> 3) << 2);
      float fa = ((t >> 2) & 1) ? s1a[r] : s0a[r];
      float fb = ((t >> 2) & 1) ? s1b[r] : s0b[r];
      float n1a = fmaf(mAa, v1a, fmaf(mBa, v2a, fa));
      float n2a = fmaf(mCa, v1a, fmaf(mDa, v2a, dsa * fa));
      float n1b = fmaf(mAb, v1b, fmaf(mBb, v2b, fb));
      float n2b = fmaf(mCb, v1b, fmaf(mDb, v2b, dsb * fb));
      v1a = n1a; v2a = n2a; v1b = n1b; v2b = n2b;
      xb[t][cola] = f2bf(v2a);
      xb[t][colb] = f2bf(v2b);
    }
    __syncthreads();

    // ---- out GEMM (16x16x32) for these 32 rows ----
    f32x4 oacc00 = {}, oacc01 = {}, oacc10 = {}, oacc11 = {};
    #pragma unroll
    for (int kt = 0; kt < 16; kt++) {
      bf16x8 af0 = *(const bf16x8*)&xb[lr][kt*32 + lk*8];
      bf16x8 af1 = *(const bf16x8*)&xb[16 + lr][kt*32 + lk*8];
      bf16x8 b0 = *(const bf16x8*)(Wc + (((size_t)(2*w    )*16 + kt)*64 + l)*8);
      bf16x8 b1 = *(const bf16x8*)(Wc + (((size_t)(2*w + 1)*16 + kt)*64 + l)*8);
      oacc00 = __builtin_amdgcn_mfma_f32_16x16x32_bf16(af0, b0, oacc00, 0, 0, 0);
      oacc01 = __builtin_amdgcn_mfma_f32_16x16x32_bf16(af1, b0, oacc01, 0, 0, 0);
      oacc10 = __builtin_amdgcn_mfma_f32_16x16x32_bf16(af0, b1, oacc10, 0, 0, 0);
      oacc11 = __builtin_amdgcn_mfma_f32_16x16x32_bf16(af1, b1, oacc11, 0, 0, 0);
    }
    size_t rows = row0 + s*32;
    #pragma unroll
    for (int i = 0; i < 2; i++) {
      int h = (2*w + i)*16 + lr;
      float Dh = i ? Dh1 : Dh0;
      f32x4 a0 = i ? oacc10 : oacc00;
      f32x4 a1 = i ? oacc11 : oacc01;
      #pragma unroll
      for (int r = 0; r < 4; r++) {
        int t0 = lk*4 + r;
        size_t idx0 = (rows + t0) * HDIM + h;
        out[idx0] = a0[r] + Dh * u[idx0];
        size_t idx1 = (rows + 16 + t0) * HDIM + h;
        out[idx1] = a1[r] + Dh * u[idx1];
      }
    }
  }
}

extern "C" void kernel_launch(void* const* d_in, const int* in_sizes, int n_in,
                              void* d_out, int out_size, void* d_ws, size_t ws_size,
                              hipStream_t stream) {
  const float* u      = (const float*)d_in[0];
  const float* A_diag = (const float*)d_in[1];
  const float* G_diag = (const float*)d_in[2];
  const float* dt     = (const float*)d_in[3];
  const float* B      = (const float*)d_in[4];
  const float* C      = (const float*)d_in[5];
  const float* D      = (const float*)d_in[6];
  float* out = (float*)d_out;

  char* ws = (char*)d_ws;
  float*  coef  = (float*)(ws + WS_COEF);
  float*  mpow2 = (float*)(ws + WS_MPOW2);
  ushort* Wb    = (ushort*)(ws + WS_WB);
  ushort* Wc    = (ushort*)(ws + WS_WC);
  float2* ends2 = (float2*)(ws + WS_ENDS);
  float2* carr2 = (float2*)(ws + WS_CARR);

  hipLaunchKernelGGL(prep_kernel, dim3(512), dim3(256), 0, stream,
                     A_diag, G_diag, dt, B, C, coef, mpow2, Wb, Wc);
  hipLaunchKernelGGL(ka_kernel, dim3(CHUNKS, BSZ), dim3(256), 0, stream, u, Wb, coef, ends2);
  hipLaunchKernelGGL(carry_kernel, dim3(BSZ, 2), dim3(256), 0, stream, ends2, mpow2, carr2);
  hipLaunchKernelGGL(kb_kernel, dim3(CHUNKS, BSZ), dim3(256), 0, stream, u, Wb, Wc, coef, carr2, D, out);
}